// Round 7
// baseline (1762.787 us; speedup 1.0000x reference)
//
#include <hip/hip_runtime.h>
#include <hip/hip_bf16.h>
#include <hip/hip_fp16.h>

#define NODES   50000
#define E_TRAIN 600000
#define E_SCORE 200000
#define GRID    1024
#define FILLB   128
#define GEMMB   782   // 782*64 = 50048 >= NODES

typedef unsigned short ushort_t;
typedef __attribute__((ext_vector_type(8))) short bf16x8;
typedef __attribute__((ext_vector_type(4))) float f32x4;

static __device__ __forceinline__ float bf2f(unsigned short u) {
    return __uint_as_float((unsigned int)u << 16);
}
static __device__ __forceinline__ unsigned short f2bf(float f) {
    __hip_bfloat16 h = __float2bfloat16(f);
    return *reinterpret_cast<unsigned short*>(&h);
}
static __device__ __forceinline__ unsigned short f2h(float f) {
    __half h = __float2half(f);
    return *reinterpret_cast<unsigned short*>(&h);
}
static __device__ __forceinline__ float2 u2f2(unsigned int u) {
    __half2 h = *reinterpret_cast<__half2*>(&u);
    return __half22float2(h);
}
static __device__ __forceinline__ unsigned int f22u(float a, float b) {
    __half2 h = __floats2half2_rn(a, b);
    return *reinterpret_cast<unsigned int*>(&h);
}
static __device__ __forceinline__ unsigned int f22u_bf(float a, float b) {
    return (unsigned int)f2bf(a) | ((unsigned int)f2bf(b) << 16);
}
// 8 consecutive fp32 -> bf16x8 (RNE)
static __device__ __forceinline__ bf16x8 cvt8(const float* p) {
    float4 v0 = *(const float4*)p;
    float4 v1 = *(const float4*)(p + 4);
    bf16x8 r;
    r[0] = (short)f2bf(v0.x); r[1] = (short)f2bf(v0.y);
    r[2] = (short)f2bf(v0.z); r[3] = (short)f2bf(v0.w);
    r[4] = (short)f2bf(v1.x); r[5] = (short)f2bf(v1.y);
    r[6] = (short)f2bf(v1.z); r[7] = (short)f2bf(v1.w);
    return r;
}

// Leader-based software grid barrier. Requires all GRID blocks co-resident
// (guaranteed: __launch_bounds__(256,4) caps VGPR<=128 -> 4 blocks/CU x 256 CUs
// = 1024 = GRID; LDS ~1KB). Monotonic counter, zeroed host-side per launch.
static __device__ __forceinline__ void gridbar(unsigned int* bar, unsigned int target) {
    __syncthreads();
    if (threadIdx.x == 0) {
        __threadfence();   // agent release: publish this block's writes
        __hip_atomic_fetch_add(bar, 1u, __ATOMIC_RELEASE, __HIP_MEMORY_SCOPE_AGENT);
        while (__hip_atomic_load(bar, __ATOMIC_ACQUIRE, __HIP_MEMORY_SCOPE_AGENT) < target)
            __builtin_amdgcn_s_sleep(2);
        __threadfence();   // agent acquire: invalidate stale caches
    }
    __syncthreads();
}

__global__ __launch_bounds__(256, 4) void mega_kernel(
    const void* __restrict__ x, const int* __restrict__ etrain,
    const int* __restrict__ pos, const int* __restrict__ neg,
    const void* __restrict__ W1, const void* __restrict__ b1,
    const void* __restrict__ W2, const void* __restrict__ b2,
    char* __restrict__ ws, void* __restrict__ out)
{
    // workspace layout (byte offsets; bar at 0 zeroed by host memset)
    unsigned int* bar       = (unsigned int*)(ws + 0);      //      64
    int*          counts    = (int*)(ws + 64);              // 200,000
    float*        dinv      = (float*)(ws + 200064);        // 200,000
    int*          row_start = (int*)(ws + 400064);          // 200,000
    int*          cursor    = (int*)(ws + 600064);          // 200,000
    int*          partial   = (int*)(ws + 800064);          //   4,096
    ushort_t*     W1T       = (ushort_t*)(ws + 804160);     //  32,768  [n][k] bf16
    ushort_t*     W2T       = (ushort_t*)(ws + 836928);     //  16,384  [n][k] bf16
    float*        b1f       = (float*)(ws + 853312);        //     512
    float*        b2f       = (float*)(ws + 853824);        //     256
    int*          esrc      = (int*)(ws + 854080);          // 2,400,000
    ushort_t*     g1        = (ushort_t*)(ws + 3254080);    // fp16 [N][128] 12.8 MB
    unsigned int* h1u       = (unsigned int*)(ws + 16054080);   // bf16 [N][128] 12.8 MB
    ushort_t*     g2        = (ushort_t*)(ws + 28854080);   // fp16 [N][64] 6.4 MB
    unsigned int* h2        = (unsigned int*)(ws + 35254080);   // fp16 [N][64] 6.4 MB

    const int* trow = etrain;
    const int* tcol = etrain + E_TRAIN;
    const int  t    = threadIdx.x;
    const int  b    = blockIdx.x;

    __shared__ int scanS[256];
    __shared__ int flagCnt;
    __shared__ int flagS;

    // ---------- P0: zero counts + per-block dtype vote ----------
    {
        int idx = b * 256 + t;
        if (idx < NODES) counts[idx] = 0;
        if (t == 0) flagCnt = 0;
        __syncthreads();
        unsigned int w = ((const unsigned int*)x)[t];
        int e = ((w & 0xFFFFu) >> 7) & 0xFF;
        if (e >= 100 && e <= 140) atomicAdd(&flagCnt, 1);
        __syncthreads();
        if (t == 0) flagS = (flagCnt >= 150) ? 1 : 0;
        __syncthreads();
    }
    const bool isbf = flagS != 0;
    gridbar(bar, GRID * 1);

    // ---------- P1: degree count (blocks 0..959) | weight transpose (960..1023) ----------
    if (b < 960) {
        for (int e = b * 256 + t; e < E_TRAIN; e += 960 * 256)
            atomicAdd(&counts[tcol[e]], 1);
    } else {
        int tid = (b - 960) * 256 + t;            // 0..16383
        {   // W1 [k=128][n=128] -> W1T[n][k]
            int k = tid >> 7, n = tid & 127;
            ushort_t raw = isbf ? ((const ushort_t*)W1)[tid] : f2bf(((const float*)W1)[tid]);
            W1T[n * 128 + k] = raw;
        }
        if (tid < 128 * 64) {   // W2 [k=128][n=64] -> W2T[n][k]
            int k = tid >> 6, n = tid & 63;
            ushort_t raw = isbf ? ((const ushort_t*)W2)[tid] : f2bf(((const float*)W2)[tid]);
            W2T[n * 128 + k] = raw;
        }
        if (tid < 128) b1f[tid] = isbf ? bf2f(((const ushort_t*)b1)[tid]) : ((const float*)b1)[tid];
        if (tid < 64)  b2f[tid] = isbf ? bf2f(((const ushort_t*)b2)[tid]) : ((const float*)b2)[tid];
    }
    gridbar(bar, GRID * 2);

    // ---------- P2: block-local inclusive scan of counts (+ dinv) ----------
    int nidx = b * 256 + t;
    int c = (nidx < NODES) ? counts[nidx] : 0;
    if (nidx < NODES) dinv[nidx] = rsqrtf((float)c + 1.0f);
    scanS[t] = c;
    __syncthreads();
    for (int off = 1; off < 256; off <<= 1) {
        int v = (t >= off) ? scanS[t - off] : 0;
        __syncthreads();
        scanS[t] += v;
        __syncthreads();
    }
    int lexcl = scanS[t] - c;
    if (t == 255) partial[b] = scanS[255];
    gridbar(bar, GRID * 3);

    // ---------- P3: block 0 scans the 1024 block sums ----------
    if (b == 0) {
        int p0 = partial[4 * t], p1 = partial[4 * t + 1];
        int p2 = partial[4 * t + 2], p3 = partial[4 * t + 3];
        int tsum = p0 + p1 + p2 + p3;
        scanS[t] = tsum;
        __syncthreads();
        for (int off = 1; off < 256; off <<= 1) {
            int v = (t >= off) ? scanS[t - off] : 0;
            __syncthreads();
            scanS[t] += v;
            __syncthreads();
        }
        int texcl = scanS[t] - tsum;
        partial[4 * t]     = texcl;
        partial[4 * t + 1] = texcl + p0;
        partial[4 * t + 2] = texcl + p0 + p1;
        partial[4 * t + 3] = texcl + p0 + p1 + p2;
    }
    gridbar(bar, GRID * 4);

    // ---------- P4: write row_start / cursor ----------
    if (nidx < NODES) {
        int basev = partial[b] + lexcl;
        row_start[nidx] = basev;
        cursor[nidx]    = basev;
    }
    gridbar(bar, GRID * 5);

    // ---------- P5: CSR fill (0..127) || GEMM1 MFMA (128..909) ----------
    if (b < FILLB) {
        for (int e = b * 256 + t; e < E_TRAIN; e += FILLB * 256) {
            int d = tcol[e];
            int p = atomicAdd(&cursor[d], 1);
            esrc[p] = trow[e];
        }
    } else if (b < FILLB + GEMMB) {
        const int bb = b - FILLB;
        const int lane = t & 63, wave = t >> 6;
        const int n = lane & 15, quad = lane >> 4;
        const int wr0 = bb * 64 + wave * 16;
        int rowA = wr0 + n; if (rowA > NODES - 1) rowA = NODES - 1;
        f32x4 acc[8];
        #pragma unroll
        for (int ct = 0; ct < 8; ++ct) acc[ct] = (f32x4){0.f, 0.f, 0.f, 0.f};
        #pragma unroll
        for (int kc = 0; kc < 4; ++kc) {
            bf16x8 a;
            if (isbf) a = *(const bf16x8*)((const ushort_t*)x + (long)rowA * 128 + kc * 32 + quad * 8);
            else      a = cvt8((const float*)x + (long)rowA * 128 + kc * 32 + quad * 8);
            #pragma unroll
            for (int ct = 0; ct < 8; ++ct) {
                bf16x8 bf = *(const bf16x8*)(W1T + (ct * 16 + n) * 128 + kc * 32 + quad * 8);
                acc[ct] = __builtin_amdgcn_mfma_f32_16x16x32_bf16(a, bf, acc[ct], 0, 0, 0);
            }
        }
        float sc[4]; int orow[4];
        #pragma unroll
        for (int r = 0; r < 4; ++r) {
            orow[r] = wr0 + quad * 4 + r;
            sc[r] = (orow[r] < NODES) ? dinv[orow[r]] : 0.f;
        }
        #pragma unroll
        for (int ct = 0; ct < 8; ++ct)
            #pragma unroll
            for (int r = 0; r < 4; ++r)
                if (orow[r] < NODES)
                    g1[(long)orow[r] * 128 + ct * 16 + n] = f2h(acc[ct][r] * sc[r]);
    }
    gridbar(bar, GRID * 6);

    // ---------- P6: gather layer 1 (wave per dest) -> h1 bf16 ----------
    {
        const unsigned int* g1u = (const unsigned int*)g1;
        int waveid = b * 4 + (t >> 6);
        int l = t & 63;
        for (int d = waveid; d < NODES; d += GRID * 4) {
            int start = row_start[d], cnt = counts[d];
            float2 acc = make_float2(0.f, 0.f);
            int j = 0;
            for (; j + 4 <= cnt; j += 4) {
                int s0 = esrc[start + j + 0], s1 = esrc[start + j + 1];
                int s2 = esrc[start + j + 2], s3 = esrc[start + j + 3];
                float2 f0 = u2f2(g1u[(long)s0 * 64 + l]);
                float2 f1 = u2f2(g1u[(long)s1 * 64 + l]);
                float2 f2 = u2f2(g1u[(long)s2 * 64 + l]);
                float2 f3 = u2f2(g1u[(long)s3 * 64 + l]);
                acc.x += (f0.x + f1.x) + (f2.x + f3.x);
                acc.y += (f0.y + f1.y) + (f2.y + f3.y);
            }
            for (; j < cnt; ++j) {
                float2 f = u2f2(g1u[(long)esrc[start + j] * 64 + l]);
                acc.x += f.x; acc.y += f.y;
            }
            float2 gd = u2f2(g1u[(long)d * 64 + l]);
            float di = dinv[d];
            float2 bia = *(const float2*)&b1f[2 * l];
            float v0 = fmaxf(di * (acc.x + gd.x) + bia.x, 0.f);
            float v1 = fmaxf(di * (acc.y + gd.y) + bia.y, 0.f);
            h1u[(long)d * 64 + l] = f22u_bf(v0, v1);
        }
    }
    gridbar(bar, GRID * 7);

    // ---------- P7: GEMM2 MFMA (blocks 0..781): g2 = dinv*(h1 @ W2) fp16 ----------
    if (b < GEMMB) {
        const ushort_t* hu = (const ushort_t*)h1u;
        const int lane = t & 63, wave = t >> 6;
        const int n = lane & 15, quad = lane >> 4;
        const int wr0 = b * 64 + wave * 16;
        int rowA = wr0 + n; if (rowA > NODES - 1) rowA = NODES - 1;
        f32x4 acc[4];
        #pragma unroll
        for (int ct = 0; ct < 4; ++ct) acc[ct] = (f32x4){0.f, 0.f, 0.f, 0.f};
        #pragma unroll
        for (int kc = 0; kc < 4; ++kc) {
            bf16x8 a = *(const bf16x8*)(hu + (long)rowA * 128 + kc * 32 + quad * 8);
            #pragma unroll
            for (int ct = 0; ct < 4; ++ct) {
                bf16x8 bf = *(const bf16x8*)(W2T + (ct * 16 + n) * 128 + kc * 32 + quad * 8);
                acc[ct] = __builtin_amdgcn_mfma_f32_16x16x32_bf16(a, bf, acc[ct], 0, 0, 0);
            }
        }
        float sc[4]; int orow[4];
        #pragma unroll
        for (int r = 0; r < 4; ++r) {
            orow[r] = wr0 + quad * 4 + r;
            sc[r] = (orow[r] < NODES) ? dinv[orow[r]] : 0.f;
        }
        #pragma unroll
        for (int ct = 0; ct < 4; ++ct)
            #pragma unroll
            for (int r = 0; r < 4; ++r)
                if (orow[r] < NODES)
                    g2[(long)orow[r] * 64 + ct * 16 + n] = f2h(acc[ct][r] * sc[r]);
    }
    gridbar(bar, GRID * 8);

    // ---------- P8: gather layer 2 (half-wave per dest) -> h2 fp16 ----------
    {
        const unsigned int* g2u = (const unsigned int*)g2;
        int swid = b * 8 + (t >> 5);
        int l = t & 31;
        for (int d = swid; d < NODES; d += GRID * 8) {
            int start = row_start[d], cnt = counts[d];
            float2 acc = make_float2(0.f, 0.f);
            int j = 0;
            for (; j + 4 <= cnt; j += 4) {
                int s0 = esrc[start + j + 0], s1 = esrc[start + j + 1];
                int s2 = esrc[start + j + 2], s3 = esrc[start + j + 3];
                float2 f0 = u2f2(g2u[(long)s0 * 32 + l]);
                float2 f1 = u2f2(g2u[(long)s1 * 32 + l]);
                float2 f2 = u2f2(g2u[(long)s2 * 32 + l]);
                float2 f3 = u2f2(g2u[(long)s3 * 32 + l]);
                acc.x += (f0.x + f1.x) + (f2.x + f3.x);
                acc.y += (f0.y + f1.y) + (f2.y + f3.y);
            }
            for (; j < cnt; ++j) {
                float2 f = u2f2(g2u[(long)esrc[start + j] * 32 + l]);
                acc.x += f.x; acc.y += f.y;
            }
            float2 gd = u2f2(g2u[(long)d * 32 + l]);
            float di = dinv[d];
            float2 bia = *(const float2*)&b2f[2 * l];
            h2[(long)d * 32 + l] = f22u(di * (acc.x + gd.x) + bia.x,
                                        di * (acc.y + gd.y) + bia.y);
        }
    }
    gridbar(bar, GRID * 9);

    // ---------- P9: scoring ----------
    for (int e = b * 256 + t; e < 2 * E_SCORE; e += GRID * 256) {
        int s, d;
        if (e < E_SCORE) { s = pos[e];           d = pos[E_SCORE + e]; }
        else             { int i = e - E_SCORE; s = neg[i]; d = neg[E_SCORE + i]; }
        const uint4* A = (const uint4*)(h2 + (long)s * 32);
        const uint4* B = (const uint4*)(h2 + (long)d * 32);
        float acc = 0.f;
        #pragma unroll
        for (int q = 0; q < 8; ++q) {
            uint4 ua = A[q], ub = B[q];
            float2 a0 = u2f2(ua.x), b0 = u2f2(ub.x);
            float2 a1 = u2f2(ua.y), b1v = u2f2(ub.y);
            float2 a2 = u2f2(ua.z), b2v = u2f2(ub.z);
            float2 a3 = u2f2(ua.w), b3 = u2f2(ub.w);
            acc += a0.x * b0.x + a0.y * b0.y + a1.x * b1v.x + a1.y * b1v.y
                 + a2.x * b2v.x + a2.y * b2v.y + a3.x * b3.x + a3.y * b3.y;
        }
        if (isbf) ((ushort_t*)out)[e] = f2bf(acc);
        else      ((float*)out)[e] = acc;
    }
}

extern "C" void kernel_launch(void* const* d_in, const int* in_sizes, int n_in,
                              void* d_out, int out_size, void* d_ws, size_t ws_size,
                              hipStream_t stream) {
    const void* x      = d_in[0];
    const int*  etrain = (const int*)d_in[1];
    const int*  pos    = (const int*)d_in[2];
    const int*  neg    = (const int*)d_in[3];
    const void* W1     = d_in[4];
    const void* b1     = d_in[5];
    const void* W2     = d_in[6];
    const void* b2     = d_in[7];
    char*       ws     = (char*)d_ws;

    hipMemsetAsync(ws, 0, 64, stream);   // zero the grid-barrier counter

    mega_kernel<<<GRID, 256, 0, stream>>>(x, etrain, pos, neg, W1, b1, W2, b2,
                                          ws, d_out);
}

// Round 8
// 341.615 us; speedup vs baseline: 5.1602x; 5.1602x over previous
//
#include <hip/hip_runtime.h>
#include <hip/hip_bf16.h>
#include <hip/hip_fp16.h>

#define NODES   50000
#define E_TRAIN 600000
#define E_SCORE 200000
#define FILLB   128
#define GEMMB   782   // 782*64 = 50048 >= NODES

typedef unsigned short ushort_t;
typedef __attribute__((ext_vector_type(8))) short bf16x8;
typedef __attribute__((ext_vector_type(4))) float f32x4;

static __device__ __forceinline__ float bf2f(unsigned short u) {
    return __uint_as_float((unsigned int)u << 16);
}
static __device__ __forceinline__ unsigned short f2bf(float f) {
    __hip_bfloat16 h = __float2bfloat16(f);
    return *reinterpret_cast<unsigned short*>(&h);
}
static __device__ __forceinline__ unsigned short f2h(float f) {
    __half h = __float2half(f);
    return *reinterpret_cast<unsigned short*>(&h);
}
static __device__ __forceinline__ float2 u2f2(unsigned int u) {
    __half2 h = *reinterpret_cast<__half2*>(&u);
    return __half22float2(h);
}
static __device__ __forceinline__ unsigned int f22u(float a, float b) {
    __half2 h = __floats2half2_rn(a, b);
    return *reinterpret_cast<unsigned int*>(&h);
}
static __device__ __forceinline__ unsigned int f22u_bf(float a, float b) {
    return (unsigned int)f2bf(a) | ((unsigned int)f2bf(b) << 16);
}
// 8 consecutive fp32 -> bf16x8 (RNE)
static __device__ __forceinline__ bf16x8 cvt8(const float* p) {
    float4 v0 = *(const float4*)p;
    float4 v1 = *(const float4*)(p + 4);
    bf16x8 r;
    r[0] = (short)f2bf(v0.x); r[1] = (short)f2bf(v0.y);
    r[2] = (short)f2bf(v0.z); r[3] = (short)f2bf(v0.w);
    r[4] = (short)f2bf(v1.x); r[5] = (short)f2bf(v1.y);
    r[6] = (short)f2bf(v1.z); r[7] = (short)f2bf(v1.w);
    return r;
}

// ======== K1: degree count (blocks 0..895) | detect + weight transpose (896..959) ====
__global__ __launch_bounds__(256) void k1_deg_w(
    const int* __restrict__ tcol, int* __restrict__ counts,
    const unsigned int* __restrict__ xw,
    const void* __restrict__ W1, const void* __restrict__ b1,
    const void* __restrict__ W2, const void* __restrict__ b2,
    ushort_t* __restrict__ W1T, ushort_t* __restrict__ W2T,
    float* __restrict__ b1f, float* __restrict__ b2f, int* __restrict__ flag)
{
    const int b = blockIdx.x, t = threadIdx.x;
    if (b < 896) {
        for (int e = b * 256 + t; e < E_TRAIN; e += 896 * 256)
            atomicAdd(&counts[tcol[e]], 1);
        return;
    }
    // local dtype vote (x[0..255] words: bf16 data -> low u16 exponent in [100,140])
    __shared__ int cnt;
    if (t == 0) cnt = 0;
    __syncthreads();
    unsigned int w = xw[t];
    int e = ((w & 0xFFFFu) >> 7) & 0xFF;
    if (e >= 100 && e <= 140) atomicAdd(&cnt, 1);
    __syncthreads();
    const bool isbf = cnt >= 150;
    if (b == 896 && t == 0) flag[0] = isbf ? 1 : 0;

    int tid = (b - 896) * 256 + t;              // 0..16383
    {   // W1 [k=128][n=128] -> W1T[n][k] bf16
        int k = tid >> 7, n = tid & 127;
        W1T[n * 128 + k] = isbf ? ((const ushort_t*)W1)[tid] : f2bf(((const float*)W1)[tid]);
    }
    if (tid < 128 * 64) {   // W2 [k=128][n=64] -> W2T[n][k] bf16
        int k = tid >> 6, n = tid & 63;
        W2T[n * 128 + k] = isbf ? ((const ushort_t*)W2)[tid] : f2bf(((const float*)W2)[tid]);
    }
    if (tid < 128) b1f[tid] = isbf ? bf2f(((const ushort_t*)b1)[tid]) : ((const float*)b1)[tid];
    if (tid < 64)  b2f[tid] = isbf ? bf2f(((const ushort_t*)b2)[tid]) : ((const float*)b2)[tid];
}

// ======== K2: exclusive scan of counts -> row_start, cursor (1 block x 1024) ========
__global__ __launch_bounds__(1024) void k2_scan(
    const int* __restrict__ counts, int* __restrict__ row_start, int* __restrict__ cursor)
{
    __shared__ int ts[1024];
    const int t = threadIdx.x;
    const int CH = 49;                           // 1024*49 >= 50000
    int base = t * CH;
    int s = 0;
    for (int i = 0; i < CH; ++i) {
        int idx = base + i;
        if (idx < NODES) s += counts[idx];
    }
    ts[t] = s;
    __syncthreads();
    for (int off = 1; off < 1024; off <<= 1) {
        int v = (t >= off) ? ts[t - off] : 0;
        __syncthreads();
        ts[t] += v;
        __syncthreads();
    }
    int run = ts[t] - s;                         // exclusive prefix
    for (int i = 0; i < CH; ++i) {
        int idx = base + i;
        if (idx >= NODES) break;
        row_start[idx] = run;
        cursor[idx]    = run;
        run += counts[idx];
    }
}

// ======== K3: CSR fill (blocks 0..127) || GEMM1 MFMA (blocks 128..909) ========
__global__ __launch_bounds__(256) void k3_fill_gemm1(
    const int* __restrict__ trow, const int* __restrict__ tcol,
    int* __restrict__ cursor, int* __restrict__ esrc,
    const void* __restrict__ x, const ushort_t* __restrict__ W1T,
    const int* __restrict__ counts, ushort_t* __restrict__ g1,
    const int* __restrict__ flag)
{
    const int t = threadIdx.x;
    if (blockIdx.x < FILLB) {
        for (int e = blockIdx.x * 256 + t; e < E_TRAIN; e += FILLB * 256) {
            int d = tcol[e];
            int p = atomicAdd(&cursor[d], 1);
            esrc[p] = trow[e];
        }
        return;
    }
    const int bb = blockIdx.x - FILLB;           // 0..781
    const bool isbf = flag[0] != 0;
    const int lane = t & 63, wave = t >> 6;
    const int n = lane & 15, quad = lane >> 4;
    const int wr0 = bb * 64 + wave * 16;
    int rowA = wr0 + n; if (rowA > NODES - 1) rowA = NODES - 1;
    f32x4 acc[8];
    #pragma unroll
    for (int ct = 0; ct < 8; ++ct) acc[ct] = (f32x4){0.f, 0.f, 0.f, 0.f};
    #pragma unroll
    for (int kc = 0; kc < 4; ++kc) {
        bf16x8 a;
        if (isbf) a = *(const bf16x8*)((const ushort_t*)x + (long)rowA * 128 + kc * 32 + quad * 8);
        else      a = cvt8((const float*)x + (long)rowA * 128 + kc * 32 + quad * 8);
        #pragma unroll
        for (int ct = 0; ct < 8; ++ct) {
            bf16x8 bv = *(const bf16x8*)(W1T + (ct * 16 + n) * 128 + kc * 32 + quad * 8);
            acc[ct] = __builtin_amdgcn_mfma_f32_16x16x32_bf16(a, bv, acc[ct], 0, 0, 0);
        }
    }
    float sc[4]; int orow[4];
    #pragma unroll
    for (int r = 0; r < 4; ++r) {
        orow[r] = wr0 + quad * 4 + r;
        sc[r] = (orow[r] < NODES) ? rsqrtf((float)counts[orow[r]] + 1.0f) : 0.f;
    }
    #pragma unroll
    for (int ct = 0; ct < 8; ++ct)
        #pragma unroll
        for (int r = 0; r < 4; ++r)
            if (orow[r] < NODES)
                g1[(long)orow[r] * 128 + ct * 16 + n] = f2h(acc[ct][r] * sc[r]);
}

// ======== K4: fused gather1 + GEMM2 (16 dests/block; 3125*16 = 50000 exact) ========
// Phase A: wave w gathers 4 dest rows -> h1 (relu, bf16) into LDS.
// Phase B: wave w computes g2[16 dests][w*16..w*16+15] via 4 MFMAs (A=LDS, B=W2T).
__global__ __launch_bounds__(256) void k4_gather1_gemm2(
    const unsigned int* __restrict__ g1u, const int* __restrict__ row_start,
    const int* __restrict__ counts, const int* __restrict__ esrc,
    const float* __restrict__ b1f, const ushort_t* __restrict__ W2T,
    ushort_t* __restrict__ g2)
{
    __shared__ ushort_t h1S[16][136];            // +8 bf16 pad
    const int t = threadIdx.x;
    const int lane = t & 63, wave = t >> 6;
    const int d0 = blockIdx.x * 16;

    #pragma unroll
    for (int i = 0; i < 4; ++i) {
        const int r = wave * 4 + i;
        const int d = d0 + r;
        const int start = row_start[d], cnt = counts[d];
        float2 acc = make_float2(0.f, 0.f);
        int j = 0;
        for (; j + 4 <= cnt; j += 4) {
            int s0 = esrc[start + j + 0], s1 = esrc[start + j + 1];
            int s2 = esrc[start + j + 2], s3 = esrc[start + j + 3];
            float2 f0 = u2f2(g1u[(long)s0 * 64 + lane]);
            float2 f1 = u2f2(g1u[(long)s1 * 64 + lane]);
            float2 f2 = u2f2(g1u[(long)s2 * 64 + lane]);
            float2 f3 = u2f2(g1u[(long)s3 * 64 + lane]);
            acc.x += (f0.x + f1.x) + (f2.x + f3.x);
            acc.y += (f0.y + f1.y) + (f2.y + f3.y);
        }
        for (; j < cnt; ++j) {
            float2 f = u2f2(g1u[(long)esrc[start + j] * 64 + lane]);
            acc.x += f.x; acc.y += f.y;
        }
        float2 gd = u2f2(g1u[(long)d * 64 + lane]);
        float di = rsqrtf((float)cnt + 1.0f);
        float2 bia = *(const float2*)&b1f[2 * lane];
        float v0 = fmaxf(di * (acc.x + gd.x) + bia.x, 0.f);
        float v1 = fmaxf(di * (acc.y + gd.y) + bia.y, 0.f);
        *(unsigned int*)&h1S[r][2 * lane] = f22u_bf(v0, v1);
    }
    __syncthreads();

    // MFMA: A row m = lane&15 (dest), B col = lane&15 within tile wave*16
    const int n = lane & 15, quad = lane >> 4;
    f32x4 acc = (f32x4){0.f, 0.f, 0.f, 0.f};
    #pragma unroll
    for (int kc = 0; kc < 4; ++kc) {
        bf16x8 a = *(const bf16x8*)&h1S[n][kc * 32 + quad * 8];
        bf16x8 bv = *(const bf16x8*)(W2T + (wave * 16 + n) * 128 + kc * 32 + quad * 8);
        acc = __builtin_amdgcn_mfma_f32_16x16x32_bf16(a, bv, acc, 0, 0, 0);
    }
    #pragma unroll
    for (int r = 0; r < 4; ++r) {
        int d = d0 + quad * 4 + r;
        float sc = rsqrtf((float)counts[d] + 1.0f);
        g2[(long)d * 64 + wave * 16 + n] = f2h(acc[r] * sc);
    }
}

// ======== K5: gather layer 2 (half-wave per dest; 6250*8 = 50000 exact) ========
__global__ __launch_bounds__(256) void k5_gather2(
    const unsigned int* __restrict__ g2u, const int* __restrict__ row_start,
    const int* __restrict__ counts, const int* __restrict__ esrc,
    const float* __restrict__ b2f, unsigned int* __restrict__ h2)
{
    const int d = blockIdx.x * 8 + (threadIdx.x >> 5);
    const int l = threadIdx.x & 31;
    const int start = row_start[d], cnt = counts[d];
    float2 acc = make_float2(0.f, 0.f);
    int j = 0;
    for (; j + 4 <= cnt; j += 4) {
        int s0 = esrc[start + j + 0], s1 = esrc[start + j + 1];
        int s2 = esrc[start + j + 2], s3 = esrc[start + j + 3];
        float2 f0 = u2f2(g2u[(long)s0 * 32 + l]);
        float2 f1 = u2f2(g2u[(long)s1 * 32 + l]);
        float2 f2 = u2f2(g2u[(long)s2 * 32 + l]);
        float2 f3 = u2f2(g2u[(long)s3 * 32 + l]);
        acc.x += (f0.x + f1.x) + (f2.x + f3.x);
        acc.y += (f0.y + f1.y) + (f2.y + f3.y);
    }
    for (; j < cnt; ++j) {
        float2 f = u2f2(g2u[(long)esrc[start + j] * 32 + l]);
        acc.x += f.x; acc.y += f.y;
    }
    float2 gd = u2f2(g2u[(long)d * 32 + l]);
    float di = rsqrtf((float)cnt + 1.0f);
    float2 bia = *(const float2*)&b2f[2 * l];
    h2[(long)d * 32 + l] = f22u(di * (acc.x + gd.x) + bia.x,
                                di * (acc.y + gd.y) + bia.y);
}

// ======== K6: scoring ========
__global__ __launch_bounds__(256) void k6_score(
    const int* __restrict__ pos, const int* __restrict__ neg,
    const unsigned int* __restrict__ h2, void* __restrict__ out,
    const int* __restrict__ flag)
{
    int e = blockIdx.x * 256 + threadIdx.x;
    if (e >= 2 * E_SCORE) return;
    int s, d;
    if (e < E_SCORE) { s = pos[e];           d = pos[E_SCORE + e]; }
    else             { int i = e - E_SCORE; s = neg[i]; d = neg[E_SCORE + i]; }
    const uint4* A = (const uint4*)(h2 + (long)s * 32);
    const uint4* B = (const uint4*)(h2 + (long)d * 32);
    float acc = 0.f;
    #pragma unroll
    for (int q = 0; q < 8; ++q) {
        uint4 ua = A[q], ub = B[q];
        float2 a0 = u2f2(ua.x), b0 = u2f2(ub.x);
        float2 a1 = u2f2(ua.y), b1 = u2f2(ub.y);
        float2 a2 = u2f2(ua.z), b2 = u2f2(ub.z);
        float2 a3 = u2f2(ua.w), b3 = u2f2(ub.w);
        acc += a0.x * b0.x + a0.y * b0.y + a1.x * b1.x + a1.y * b1.y
             + a2.x * b2.x + a2.y * b2.y + a3.x * b3.x + a3.y * b3.y;
    }
    if (flag[0]) ((ushort_t*)out)[e] = f2bf(acc);
    else         ((float*)out)[e] = acc;
}

extern "C" void kernel_launch(void* const* d_in, const int* in_sizes, int n_in,
                              void* d_out, int out_size, void* d_ws, size_t ws_size,
                              hipStream_t stream) {
    const void* x      = d_in[0];
    const int*  etrain = (const int*)d_in[1];
    const int*  pos    = (const int*)d_in[2];
    const int*  neg    = (const int*)d_in[3];
    const void* W1     = d_in[4];
    const void* b1     = d_in[5];
    const void* W2     = d_in[6];
    const void* b2     = d_in[7];

    char* ws = (char*)d_ws;
    int*          flag      = (int*)(ws + 0);              //      64
    int*          counts    = (int*)(ws + 64);             // 200,000
    int*          row_start = (int*)(ws + 200064);         // 200,000
    int*          cursor    = (int*)(ws + 400064);         // 200,000
    ushort_t*     W1T       = (ushort_t*)(ws + 600064);    //  32,768
    ushort_t*     W2T       = (ushort_t*)(ws + 632832);    //  16,384
    float*        b1f       = (float*)(ws + 649216);       //     512
    float*        b2f       = (float*)(ws + 649728);       //     256
    int*          esrc      = (int*)(ws + 649984);         // 2,400,000
    ushort_t*     g1        = (ushort_t*)(ws + 3049984);   // fp16 [N][128] 12.8 MB
    ushort_t*     g2        = (ushort_t*)(ws + 15849984);  // fp16 [N][64]  6.4 MB
    unsigned int* h2        = (unsigned int*)(ws + 22249984); // fp16 [N][64] 6.4 MB

    const int* trow = etrain;
    const int* tcol = etrain + E_TRAIN;

    hipMemsetAsync(counts, 0, NODES * sizeof(int), stream);

    k1_deg_w<<<960, 256, 0, stream>>>(tcol, counts, (const unsigned int*)x,
                                      W1, b1, W2, b2, W1T, W2T, b1f, b2f, flag);

    k2_scan<<<1, 1024, 0, stream>>>(counts, row_start, cursor);

    k3_fill_gemm1<<<FILLB + GEMMB, 256, 0, stream>>>(trow, tcol, cursor, esrc,
                                                     x, W1T, counts, g1, flag);

    k4_gather1_gemm2<<<3125, 256, 0, stream>>>((const unsigned int*)g1, row_start,
                                               counts, esrc, b1f, W2T, g2);

    k5_gather2<<<6250, 256, 0, stream>>>((const unsigned int*)g2, row_start,
                                         counts, esrc, b2f, h2);

    k6_score<<<1563, 256, 0, stream>>>(pos, neg, h2, d_out, flag);
}

// Round 9
// 232.358 us; speedup vs baseline: 7.5865x; 1.4702x over previous
//
#include <hip/hip_runtime.h>
#include <hip/hip_bf16.h>
#include <hip/hip_fp16.h>

#define NODES   50000
#define E_TRAIN 600000
#define E_SCORE 200000
#define FILLB   128
#define GEMMB   782   // 782*64 = 50048 >= NODES
#define SCANB   49    // 49*1024 = 50176 >= NODES

typedef unsigned short ushort_t;
typedef __attribute__((ext_vector_type(8))) short bf16x8;
typedef __attribute__((ext_vector_type(4))) float f32x4;

static __device__ __forceinline__ float bf2f(unsigned short u) {
    return __uint_as_float((unsigned int)u << 16);
}
static __device__ __forceinline__ unsigned short f2bf(float f) {
    __hip_bfloat16 h = __float2bfloat16(f);
    return *reinterpret_cast<unsigned short*>(&h);
}
static __device__ __forceinline__ unsigned short f2h(float f) {
    __half h = __float2half(f);
    return *reinterpret_cast<unsigned short*>(&h);
}
static __device__ __forceinline__ float2 u2f2(unsigned int u) {
    __half2 h = *reinterpret_cast<__half2*>(&u);
    return __half22float2(h);
}
static __device__ __forceinline__ unsigned int f22u(float a, float b) {
    __half2 h = __floats2half2_rn(a, b);
    return *reinterpret_cast<unsigned int*>(&h);
}
static __device__ __forceinline__ unsigned int f22u_bf(float a, float b) {
    return (unsigned int)f2bf(a) | ((unsigned int)f2bf(b) << 16);
}
// 8 consecutive fp32 -> bf16x8 (RNE)
static __device__ __forceinline__ bf16x8 cvt8(const float* p) {
    float4 v0 = *(const float4*)p;
    float4 v1 = *(const float4*)(p + 4);
    bf16x8 r;
    r[0] = (short)f2bf(v0.x); r[1] = (short)f2bf(v0.y);
    r[2] = (short)f2bf(v0.z); r[3] = (short)f2bf(v0.w);
    r[4] = (short)f2bf(v1.x); r[5] = (short)f2bf(v1.y);
    r[6] = (short)f2bf(v1.z); r[7] = (short)f2bf(v1.w);
    return r;
}

// ======== K1: degree count (blocks 0..895) | detect + weight transpose (896..959) ====
__global__ __launch_bounds__(256) void k1_deg_w(
    const int* __restrict__ tcol, int* __restrict__ counts,
    const unsigned int* __restrict__ xw,
    const void* __restrict__ W1, const void* __restrict__ b1,
    const void* __restrict__ W2, const void* __restrict__ b2,
    ushort_t* __restrict__ W1T, ushort_t* __restrict__ W2T,
    float* __restrict__ b1f, float* __restrict__ b2f, int* __restrict__ flag)
{
    const int b = blockIdx.x, t = threadIdx.x;
    if (b < 896) {
        for (int e = b * 256 + t; e < E_TRAIN; e += 896 * 256)
            atomicAdd(&counts[tcol[e]], 1);
        return;
    }
    // local dtype vote (x[0..255] words: bf16 data -> low u16 exponent in [100,140])
    __shared__ int cnt;
    if (t == 0) cnt = 0;
    __syncthreads();
    unsigned int w = xw[t];
    int e = ((w & 0xFFFFu) >> 7) & 0xFF;
    if (e >= 100 && e <= 140) atomicAdd(&cnt, 1);
    __syncthreads();
    const bool isbf = cnt >= 150;
    if (b == 896 && t == 0) flag[0] = isbf ? 1 : 0;

    int tid = (b - 896) * 256 + t;              // 0..16383
    {   // W1 [k=128][n=128] -> W1T[n][k] bf16
        int k = tid >> 7, n = tid & 127;
        W1T[n * 128 + k] = isbf ? ((const ushort_t*)W1)[tid] : f2bf(((const float*)W1)[tid]);
    }
    if (tid < 128 * 64) {   // W2 [k=128][n=64] -> W2T[n][k] bf16
        int k = tid >> 6, n = tid & 63;
        W2T[n * 128 + k] = isbf ? ((const ushort_t*)W2)[tid] : f2bf(((const float*)W2)[tid]);
    }
    if (tid < 128) b1f[tid] = isbf ? bf2f(((const ushort_t*)b1)[tid]) : ((const float*)b1)[tid];
    if (tid < 64)  b2f[tid] = isbf ? bf2f(((const ushort_t*)b2)[tid]) : ((const float*)b2)[tid];
}

// ======== K2: single-pass lookback scan (49 blocks x 256, 1024 nodes/block) ========
// agg[] zeroed host-side; block publishes (blocksum+1) then lanes 0..48 of wave 0
// spin-read preceding aggregates concurrently and butterfly-reduce.
__global__ __launch_bounds__(256) void k2_scan(
    const int* __restrict__ counts, int* __restrict__ row_start,
    int* __restrict__ cursor, int* __restrict__ agg)
{
    const int b = blockIdx.x, t = threadIdx.x;
    const int base = b * 1024 + t * 4;
    int4 c4 = make_int4(0, 0, 0, 0);
    if (base + 3 < NODES) c4 = *(const int4*)(counts + base);
    else {
        if (base + 0 < NODES) c4.x = counts[base + 0];
        if (base + 1 < NODES) c4.y = counts[base + 1];
        if (base + 2 < NODES) c4.z = counts[base + 2];
        if (base + 3 < NODES) c4.w = counts[base + 3];
    }
    int tsum = c4.x + c4.y + c4.z + c4.w;

    __shared__ int ts[256];
    __shared__ int prefS;
    ts[t] = tsum;
    __syncthreads();
    for (int off = 1; off < 256; off <<= 1) {
        int v = (t >= off) ? ts[t - off] : 0;
        __syncthreads();
        ts[t] += v;
        __syncthreads();
    }
    int lexcl = ts[t] - tsum;        // exclusive prefix within block
    int bsum  = ts[255];

    if (t == 0)
        __hip_atomic_store(&agg[b], bsum + 1, __ATOMIC_RELEASE, __HIP_MEMORY_SCOPE_AGENT);

    if (t < 64) {
        int v = 0;
        if (t < b) {
            int a;
            do {
                a = __hip_atomic_load(&agg[t], __ATOMIC_ACQUIRE, __HIP_MEMORY_SCOPE_AGENT);
            } while (a == 0);
            v = a - 1;
        }
        #pragma unroll
        for (int off = 32; off > 0; off >>= 1) v += __shfl_xor(v, off, 64);
        if (t == 0) prefS = v;
    }
    __syncthreads();

    int r0 = prefS + lexcl;
    if (base + 0 < NODES) { row_start[base + 0] = r0; cursor[base + 0] = r0; } r0 += c4.x;
    if (base + 1 < NODES) { row_start[base + 1] = r0; cursor[base + 1] = r0; } r0 += c4.y;
    if (base + 2 < NODES) { row_start[base + 2] = r0; cursor[base + 2] = r0; } r0 += c4.z;
    if (base + 3 < NODES) { row_start[base + 3] = r0; cursor[base + 3] = r0; }
}

// ======== K3: CSR fill (blocks 0..127) || GEMM1 MFMA (blocks 128..909) ========
__global__ __launch_bounds__(256) void k3_fill_gemm1(
    const int* __restrict__ trow, const int* __restrict__ tcol,
    int* __restrict__ cursor, int* __restrict__ esrc,
    const void* __restrict__ x, const ushort_t* __restrict__ W1T,
    const int* __restrict__ counts, ushort_t* __restrict__ g1,
    const int* __restrict__ flag)
{
    const int t = threadIdx.x;
    if (blockIdx.x < FILLB) {
        for (int e = blockIdx.x * 256 + t; e < E_TRAIN; e += FILLB * 256) {
            int d = tcol[e];
            int p = atomicAdd(&cursor[d], 1);
            esrc[p] = trow[e];
        }
        return;
    }
    const int bb = blockIdx.x - FILLB;           // 0..781
    const bool isbf = flag[0] != 0;
    const int lane = t & 63, wave = t >> 6;
    const int n = lane & 15, quad = lane >> 4;
    const int wr0 = bb * 64 + wave * 16;
    int rowA = wr0 + n; if (rowA > NODES - 1) rowA = NODES - 1;
    f32x4 acc[8];
    #pragma unroll
    for (int ct = 0; ct < 8; ++ct) acc[ct] = (f32x4){0.f, 0.f, 0.f, 0.f};
    #pragma unroll
    for (int kc = 0; kc < 4; ++kc) {
        bf16x8 a;
        if (isbf) a = *(const bf16x8*)((const ushort_t*)x + (long)rowA * 128 + kc * 32 + quad * 8);
        else      a = cvt8((const float*)x + (long)rowA * 128 + kc * 32 + quad * 8);
        #pragma unroll
        for (int ct = 0; ct < 8; ++ct) {
            bf16x8 bv = *(const bf16x8*)(W1T + (ct * 16 + n) * 128 + kc * 32 + quad * 8);
            acc[ct] = __builtin_amdgcn_mfma_f32_16x16x32_bf16(a, bv, acc[ct], 0, 0, 0);
        }
    }
    float sc[4]; int orow[4];
    #pragma unroll
    for (int r = 0; r < 4; ++r) {
        orow[r] = wr0 + quad * 4 + r;
        sc[r] = (orow[r] < NODES) ? rsqrtf((float)counts[orow[r]] + 1.0f) : 0.f;
    }
    #pragma unroll
    for (int ct = 0; ct < 8; ++ct)
        #pragma unroll
        for (int r = 0; r < 4; ++r)
            if (orow[r] < NODES)
                g1[(long)orow[r] * 128 + ct * 16 + n] = f2h(acc[ct][r] * sc[r]);
}

// ======== K4: fused gather1 + GEMM2 (16 dests/block; 3125*16 = 50000 exact) ========
__global__ __launch_bounds__(256) void k4_gather1_gemm2(
    const unsigned int* __restrict__ g1u, const int* __restrict__ row_start,
    const int* __restrict__ counts, const int* __restrict__ esrc,
    const float* __restrict__ b1f, const ushort_t* __restrict__ W2T,
    ushort_t* __restrict__ g2)
{
    __shared__ ushort_t h1S[16][136];            // +8 bf16 pad
    const int t = threadIdx.x;
    const int lane = t & 63, wave = t >> 6;
    const int d0 = blockIdx.x * 16;

    #pragma unroll
    for (int i = 0; i < 4; ++i) {
        const int r = wave * 4 + i;
        const int d = d0 + r;
        const int start = row_start[d], cnt = counts[d];
        float2 acc = make_float2(0.f, 0.f);
        int j = 0;
        for (; j + 4 <= cnt; j += 4) {
            int s0 = esrc[start + j + 0], s1 = esrc[start + j + 1];
            int s2 = esrc[start + j + 2], s3 = esrc[start + j + 3];
            float2 f0 = u2f2(g1u[(long)s0 * 64 + lane]);
            float2 f1 = u2f2(g1u[(long)s1 * 64 + lane]);
            float2 f2 = u2f2(g1u[(long)s2 * 64 + lane]);
            float2 f3 = u2f2(g1u[(long)s3 * 64 + lane]);
            acc.x += (f0.x + f1.x) + (f2.x + f3.x);
            acc.y += (f0.y + f1.y) + (f2.y + f3.y);
        }
        for (; j < cnt; ++j) {
            float2 f = u2f2(g1u[(long)esrc[start + j] * 64 + lane]);
            acc.x += f.x; acc.y += f.y;
        }
        float2 gd = u2f2(g1u[(long)d * 64 + lane]);
        float di = rsqrtf((float)cnt + 1.0f);
        float2 bia = *(const float2*)&b1f[2 * lane];
        float v0 = fmaxf(di * (acc.x + gd.x) + bia.x, 0.f);
        float v1 = fmaxf(di * (acc.y + gd.y) + bia.y, 0.f);
        *(unsigned int*)&h1S[r][2 * lane] = f22u_bf(v0, v1);
    }
    __syncthreads();

    const int n = lane & 15, quad = lane >> 4;
    f32x4 acc = (f32x4){0.f, 0.f, 0.f, 0.f};
    #pragma unroll
    for (int kc = 0; kc < 4; ++kc) {
        bf16x8 a = *(const bf16x8*)&h1S[n][kc * 32 + quad * 8];
        bf16x8 bv = *(const bf16x8*)(W2T + (wave * 16 + n) * 128 + kc * 32 + quad * 8);
        acc = __builtin_amdgcn_mfma_f32_16x16x32_bf16(a, bv, acc, 0, 0, 0);
    }
    #pragma unroll
    for (int r = 0; r < 4; ++r) {
        int d = d0 + quad * 4 + r;
        float sc = rsqrtf((float)counts[d] + 1.0f);
        g2[(long)d * 64 + wave * 16 + n] = f2h(acc[r] * sc);
    }
}

// ======== K5: gather layer 2 (half-wave per dest; 6250*8 = 50000 exact) ========
__global__ __launch_bounds__(256) void k5_gather2(
    const unsigned int* __restrict__ g2u, const int* __restrict__ row_start,
    const int* __restrict__ counts, const int* __restrict__ esrc,
    const float* __restrict__ b2f, unsigned int* __restrict__ h2)
{
    const int d = blockIdx.x * 8 + (threadIdx.x >> 5);
    const int l = threadIdx.x & 31;
    const int start = row_start[d], cnt = counts[d];
    float2 acc = make_float2(0.f, 0.f);
    int j = 0;
    for (; j + 4 <= cnt; j += 4) {
        int s0 = esrc[start + j + 0], s1 = esrc[start + j + 1];
        int s2 = esrc[start + j + 2], s3 = esrc[start + j + 3];
        float2 f0 = u2f2(g2u[(long)s0 * 32 + l]);
        float2 f1 = u2f2(g2u[(long)s1 * 32 + l]);
        float2 f2 = u2f2(g2u[(long)s2 * 32 + l]);
        float2 f3 = u2f2(g2u[(long)s3 * 32 + l]);
        acc.x += (f0.x + f1.x) + (f2.x + f3.x);
        acc.y += (f0.y + f1.y) + (f2.y + f3.y);
    }
    for (; j < cnt; ++j) {
        float2 f = u2f2(g2u[(long)esrc[start + j] * 32 + l]);
        acc.x += f.x; acc.y += f.y;
    }
    float2 gd = u2f2(g2u[(long)d * 32 + l]);
    float di = rsqrtf((float)cnt + 1.0f);
    float2 bia = *(const float2*)&b2f[2 * l];
    h2[(long)d * 32 + l] = f22u(di * (acc.x + gd.x) + bia.x,
                                di * (acc.y + gd.y) + bia.y);
}

// ======== K6: scoring ========
__global__ __launch_bounds__(256) void k6_score(
    const int* __restrict__ pos, const int* __restrict__ neg,
    const unsigned int* __restrict__ h2, void* __restrict__ out,
    const int* __restrict__ flag)
{
    int e = blockIdx.x * 256 + threadIdx.x;
    if (e >= 2 * E_SCORE) return;
    int s, d;
    if (e < E_SCORE) { s = pos[e];           d = pos[E_SCORE + e]; }
    else             { int i = e - E_SCORE; s = neg[i]; d = neg[E_SCORE + i]; }
    const uint4* A = (const uint4*)(h2 + (long)s * 32);
    const uint4* B = (const uint4*)(h2 + (long)d * 32);
    float acc = 0.f;
    #pragma unroll
    for (int q = 0; q < 8; ++q) {
        uint4 ua = A[q], ub = B[q];
        float2 a0 = u2f2(ua.x), b0 = u2f2(ub.x);
        float2 a1 = u2f2(ua.y), b1 = u2f2(ub.y);
        float2 a2 = u2f2(ua.z), b2 = u2f2(ub.z);
        float2 a3 = u2f2(ua.w), b3 = u2f2(ub.w);
        acc += a0.x * b0.x + a0.y * b0.y + a1.x * b1.x + a1.y * b1.y
             + a2.x * b2.x + a2.y * b2.y + a3.x * b3.x + a3.y * b3.y;
    }
    if (flag[0]) ((ushort_t*)out)[e] = f2bf(acc);
    else         ((float*)out)[e] = acc;
}

extern "C" void kernel_launch(void* const* d_in, const int* in_sizes, int n_in,
                              void* d_out, int out_size, void* d_ws, size_t ws_size,
                              hipStream_t stream) {
    const void* x      = d_in[0];
    const int*  etrain = (const int*)d_in[1];
    const int*  pos    = (const int*)d_in[2];
    const int*  neg    = (const int*)d_in[3];
    const void* W1     = d_in[4];
    const void* b1     = d_in[5];
    const void* W2     = d_in[6];
    const void* b2     = d_in[7];

    char* ws = (char*)d_ws;
    int*          flag      = (int*)(ws + 0);              //      64
    int*          counts    = (int*)(ws + 64);             // 200,000
    int*          agg       = (int*)(ws + 200064);         //     256 (zeroed w/ counts)
    int*          row_start = (int*)(ws + 200320);         // 200,000
    int*          cursor    = (int*)(ws + 400320);         // 200,000
    ushort_t*     W1T       = (ushort_t*)(ws + 600320);    //  32,768
    ushort_t*     W2T       = (ushort_t*)(ws + 633088);    //  16,384
    float*        b1f       = (float*)(ws + 649472);       //     512
    float*        b2f       = (float*)(ws + 649984);       //     256
    int*          esrc      = (int*)(ws + 650240);         // 2,400,000
    ushort_t*     g1        = (ushort_t*)(ws + 3050240);   // fp16 [N][128] 12.8 MB
    ushort_t*     g2        = (ushort_t*)(ws + 15850240);  // fp16 [N][64]  6.4 MB
    unsigned int* h2        = (unsigned int*)(ws + 22250240); // fp16 [N][64] 6.4 MB

    const int* trow = etrain;
    const int* tcol = etrain + E_TRAIN;

    hipMemsetAsync(ws + 64, 0, 200256, stream);   // counts + agg

    k1_deg_w<<<960, 256, 0, stream>>>(tcol, counts, (const unsigned int*)x,
                                      W1, b1, W2, b2, W1T, W2T, b1f, b2f, flag);

    k2_scan<<<SCANB, 256, 0, stream>>>(counts, row_start, cursor, agg);

    k3_fill_gemm1<<<FILLB + GEMMB, 256, 0, stream>>>(trow, tcol, cursor, esrc,
                                                     x, W1T, counts, g1, flag);

    k4_gather1_gemm2<<<3125, 256, 0, stream>>>((const unsigned int*)g1, row_start,
                                               counts, esrc, b1f, W2T, g2);

    k5_gather2<<<6250, 256, 0, stream>>>((const unsigned int*)g2, row_start,
                                         counts, esrc, b2f, h2);

    k6_score<<<1563, 256, 0, stream>>>(pos, neg, h2, d_out, flag);
}